// Round 5
// baseline (264.425 us; speedup 1.0000x reference)
//
#include <hip/hip_runtime.h>
#include <math.h>

#define NCELL 2560
#define TAB_LO (-5.0f)
#define TAB_INVSTEP 256.0f
#define TAB_STEP 0.00390625f
#define EPSF 1e-8f
#define SCALE_128 0.08838834764831845f   // 1/sqrt(128)
#define GRID_MAIN 2048

// ---------------- table build kernel ----------------
// ws layout: ws[0] = max centroid; float4 cells at ws+16:
//   {bnd[lo] or +inf, cent[lo], cent[lo+1] (clamped), 0}
__global__ __launch_bounds__(256) void build_table(const float* __restrict__ cent,
                                                   float* __restrict__ ws) {
    __shared__ float sc[256];
    __shared__ float sb[255];
    int tid = threadIdx.x;
    sc[tid] = cent[tid];
    __syncthreads();
    if (tid < 255) sb[tid] = 0.5f * (sc[tid] + sc[tid + 1]);
    __syncthreads();
    int k = blockIdx.x * 256 + tid;
    if (k < NCELL) {
        float edge = TAB_LO + (float)k * TAB_STEP;   // exact in f32 (pow2 step)
        int lo = 0, hi = 255;                        // lower_bound: count of bnd < edge
        while (lo < hi) {
            int mid = (lo + hi) >> 1;
            if (sb[mid] < edge) lo = mid + 1; else hi = mid;
        }
        float4 cl;
        cl.x = (lo < 255) ? sb[lo] : __int_as_float(0x7f800000);  // +inf
        cl.y = sc[lo];
        cl.z = (lo < 255) ? sc[lo + 1] : sc[255];
        cl.w = 0.0f;
        ((float4*)(ws + 16))[k] = cl;
    }
    if (blockIdx.x == 0 && tid == 0) {
        float m = sc[0];
        for (int i = 1; i < 256; ++i) m = fmaxf(m, sc[i]);
        ws[0] = m;
    }
}

// ---------------- cross-lane helpers (all on the VALU pipe, zero LDS ops) ----
__device__ __forceinline__ float dpp_xor1(float x) {   // quad_perm [1,0,3,2]
    int i = __float_as_int(x);
    return __int_as_float(__builtin_amdgcn_update_dpp(i, i, 0xB1, 0xF, 0xF, true));
}
__device__ __forceinline__ float dpp_xor2(float x) {   // quad_perm [2,3,0,1]
    int i = __float_as_int(x);
    return __int_as_float(__builtin_amdgcn_update_dpp(i, i, 0x4E, 0xF, 0xF, true));
}
// xor-4 exchange, VARIANT A. Convention (AMD DPP docs + r1/r4 error-signature A/B:
// variant A scored 0.148 total [table artifact], swapped variant B scored 5.44
// [broken-transform signature]): ROW_SHL:N => dst i <- src i+N (values move toward
// lower lanes); ROW_SHR:N => dst i <- src i-N.
//   banks 0,2 ((lane&4)==0) need partner i+4 -> row_shl:4, bank_mask 0x5
//   banks 1,3 ((lane&4)==4) need partner i-4 -> row_shr:4, bank_mask 0xA
__device__ __forceinline__ float dpp_xor4(float x) {
    int i = __float_as_int(x);
    int t = __builtin_amdgcn_update_dpp(i, i, 0x104, 0xF, 0x5, false); // row_shl:4 -> banks 0,2
    t = __builtin_amdgcn_update_dpp(t, i, 0x114, 0xF, 0xA, false);     // row_shr:4 -> banks 1,3
    return __int_as_float(t);
}

__device__ __forceinline__ float rsum8(float v) {
    v += dpp_xor1(v);
    v += dpp_xor2(v);
    v += dpp_xor4(v);
    return v;
}
__device__ __forceinline__ float rmax8(float v) {
    v = fmaxf(v, dpp_xor1(v));
    v = fmaxf(v, dpp_xor2(v));
    v = fmaxf(v, dpp_xor4(v));
    return v;
}

// FWHT-128: element j = c*32 + l*4 + e; within-lane stages h=1,2 (e bits) and
// h=32,64 (c bits); cross-lane stages h=4,8,16 via DPP xor 1,2,4.
__device__ __forceinline__ void fwht128(float v[16], float s1, float s2, float s4) {
#pragma unroll
    for (int c = 0; c < 4; ++c) {           // h=1, h=2 (radix-4)
        int b = c * 4;
        float a0 = v[b], a1 = v[b + 1], a2 = v[b + 2], a3 = v[b + 3];
        float t0 = a0 + a1, t1 = a0 - a1, t2 = a2 + a3, t3 = a2 - a3;
        v[b] = t0 + t2; v[b + 1] = t1 + t3; v[b + 2] = t0 - t2; v[b + 3] = t1 - t3;
    }
#pragma unroll
    for (int i = 0; i < 16; ++i) { float t = dpp_xor1(v[i]); v[i] = fmaf(s1, v[i], t); }  // h=4
#pragma unroll
    for (int i = 0; i < 16; ++i) { float t = dpp_xor2(v[i]); v[i] = fmaf(s2, v[i], t); }  // h=8
#pragma unroll
    for (int i = 0; i < 16; ++i) { float t = dpp_xor4(v[i]); v[i] = fmaf(s4, v[i], t); }  // h=16
#pragma unroll
    for (int e = 0; e < 4; ++e) {           // h=32, h=64 (radix-4 over c)
        float a0 = v[e], a1 = v[4 + e], a2 = v[8 + e], a3 = v[12 + e];
        float t0 = a0 + a1, t1 = a0 - a1, t2 = a2 + a3, t3 = a2 - a3;
        v[e] = t0 + t2; v[4 + e] = t1 + t3; v[8 + e] = t0 - t2; v[12 + e] = t1 - t3;
    }
}

// Fused cell: one ds_read_b128 per lookup, no dependent second read.
__device__ __forceinline__ float qlook(float u, const float4* sCell) {
    float t = (u - TAB_LO) * TAB_INVSTEP;
    int k = (int)t;
    k = k < 0 ? 0 : (k > NCELL - 1 ? NCELL - 1 : k);
    float4 cl = sCell[k];
    return (cl.x < u) ? cl.z : cl.y;   // searchsorted 'left' correction
}

// ---------------- main kernel ----------------
__global__ __launch_bounds__(256) void tq_main(const float* __restrict__ x,
                                               const float* __restrict__ signs,
                                               const float* __restrict__ ws,
                                               float* __restrict__ out,
                                               int ntiles) {
    __shared__ float4 sCell[NCELL];   // 40960 B exactly -> 4 blocks/CU
    int tid = threadIdx.x;
    const float4* wcell = (const float4*)(ws + 16);
    for (int i = tid; i < NCELL; i += 256) sCell[i] = wcell[i];
    float maxc = ws[0];
    __syncthreads();

    int lane = tid & 63;
    int wv = tid >> 6;      // wave in block: 0..3
    int g = lane >> 3;      // row within wave: 0..7
    int l = lane & 7;       // lane within row-group: 0..7
    float s1 = (l & 1) ? -1.0f : 1.0f;
    float s2 = (l & 2) ? -1.0f : 1.0f;
    float s4 = (l & 4) ? -1.0f : 1.0f;

    // this lane's 16 sign values (j = c*32 + l*4 + e)
    float sg[16];
#pragma unroll
    for (int c = 0; c < 4; ++c) {
        float4 t4 = *(const float4*)(signs + c * 32 + l * 4);
        sg[c * 4 + 0] = t4.x; sg[c * 4 + 1] = t4.y; sg[c * 4 + 2] = t4.z; sg[c * 4 + 3] = t4.w;
    }

    for (int tile = blockIdx.x; tile < ntiles; tile += gridDim.x) {
        int row = tile * 32 + wv * 8 + g;
        const float* xp = x + (size_t)row * 128;
        float v[16];
#pragma unroll
        for (int c = 0; c < 4; ++c) {
            float4 t4 = *(const float4*)(xp + c * 32 + l * 4);
            v[c * 4 + 0] = t4.x; v[c * 4 + 1] = t4.y; v[c * 4 + 2] = t4.z; v[c * 4 + 3] = t4.w;
        }
        // ---- norm ----
        float ssum = 0.0f;
#pragma unroll
        for (int i = 0; i < 16; ++i) ssum = fmaf(v[i], v[i], ssum);
        ssum = rsum8(ssum);
        float norm = sqrtf(ssum) + EPSF;
        float invn = 1.0f / norm;
        // ---- rotate ----
#pragma unroll
        for (int i = 0; i < 16; ++i) v[i] = v[i] * invn * sg[i];
        fwht128(v, s1, s2, s4);
#pragma unroll
        for (int i = 0; i < 16; ++i) v[i] *= SCALE_128;
        // ---- stats ----
        float mx = 0.0f, sm = 0.0f;
#pragma unroll
        for (int i = 0; i < 16; ++i) { float a = fabsf(v[i]); mx = fmaxf(mx, a); sm += a; }
        mx = rmax8(mx);
        sm = rsum8(sm);
        float meanv = sm * 0.0078125f + EPSF;   // /128
        float rms = mx / maxc;
        bool spiky = (mx / meanv) > 5.0f;
        // ---- pass 1 ----
        float invd = 1.0f / (rms + EPSF);
        float dxr = 0.0f, drr = 0.0f;
#pragma unroll
        for (int i = 0; i < 16; ++i) {
            float r = qlook(v[i] * invd, sCell);
            dxr = fmaf(v[i], r, dxr);
            drr = fmaf(r, r, drr);
        }
        dxr = rsum8(dxr); drr = rsum8(drr);
        float g1 = dxr / (drr + EPSF);
        // ---- pass 2 ----
        float invg = 1.0f / (g1 + EPSF);
        float rr[16];
        dxr = 0.0f; drr = 0.0f;
#pragma unroll
        for (int i = 0; i < 16; ++i) {
            float r = qlook(v[i] * invg, sCell);
            rr[i] = r;
            dxr = fmaf(v[i], r, dxr);
            drr = fmaf(r, r, drr);
        }
        dxr = rsum8(dxr); drr = rsum8(drr);
        float g2 = dxr / (drr + EPSF);
        float gamma = spiky ? rms : g2;
        if (spiky) {   // rare: re-gather r1 for spiky rows
#pragma unroll
            for (int i = 0; i < 16; ++i) rr[i] = qlook(v[i] * invd, sCell);
        }
        // ---- reconstruct ----
#pragma unroll
        for (int i = 0; i < 16; ++i) rr[i] *= gamma;
        fwht128(rr, s1, s2, s4);
        float fsc = SCALE_128 * norm;
        float* op = out + (size_t)row * 128;
#pragma unroll
        for (int c = 0; c < 4; ++c) {
            float4 o4;
            o4.x = rr[c * 4 + 0] * sg[c * 4 + 0] * fsc;
            o4.y = rr[c * 4 + 1] * sg[c * 4 + 1] * fsc;
            o4.z = rr[c * 4 + 2] * sg[c * 4 + 2] * fsc;
            o4.w = rr[c * 4 + 3] * sg[c * 4 + 3] * fsc;
            *(float4*)(op + c * 32 + l * 4) = o4;
        }
    }
}

extern "C" void kernel_launch(void* const* d_in, const int* in_sizes, int n_in,
                              void* d_out, int out_size, void* d_ws, size_t ws_size,
                              hipStream_t stream) {
    const float* x     = (const float*)d_in[0];
    const float* signs = (const float*)d_in[1];
    const float* cent  = (const float*)d_in[2];
    float* out = (float*)d_out;
    float* ws  = (float*)d_ws;

    int nrows  = in_sizes[0] / 128;
    int ntiles = nrows / 32;     // 32 rows per block-iteration (4 waves x 8 rows)

    build_table<<<(NCELL + 255) / 256, 256, 0, stream>>>(cent, ws);
    int grid = ntiles < GRID_MAIN ? ntiles : GRID_MAIN;
    tq_main<<<grid, 256, 0, stream>>>(x, signs, ws, out, ntiles);
}

// Round 6
// 261.984 us; speedup vs baseline: 1.0093x; 1.0093x over previous
//
#include <hip/hip_runtime.h>
#include <math.h>

#define NCELL 1280
#define TAB_LO (-5.0f)
#define TAB_INVSTEP 128.0f
#define TAB_STEP 0.0078125f
#define EPSF 1e-8f
#define SCALE_128 0.08838834764831845f   // 1/sqrt(128)
#define GRID_MAIN 2048

// ---------------- table build kernel ----------------
// ws layout: ws[0] = max centroid; float4 cells at ws+16:
//   {bnd[lo] or +inf, cent[lo], cent[lo+1] (clamped), 0}
// Cell width 2^-7 = 0.0078 < min Lloyd-Max boundary spacing (~0.017 at center),
// so every cell contains at most one boundary -> single-compare correction valid.
__global__ __launch_bounds__(256) void build_table(const float* __restrict__ cent,
                                                   float* __restrict__ ws) {
    __shared__ float sc[256];
    __shared__ float sb[255];
    int tid = threadIdx.x;
    sc[tid] = cent[tid];
    __syncthreads();
    if (tid < 255) sb[tid] = 0.5f * (sc[tid] + sc[tid + 1]);
    __syncthreads();
    int k = blockIdx.x * 256 + tid;
    if (k < NCELL) {
        float edge = TAB_LO + (float)k * TAB_STEP;   // exact in f32 (pow2 step)
        int lo = 0, hi = 255;                        // lower_bound: count of bnd < edge
        while (lo < hi) {
            int mid = (lo + hi) >> 1;
            if (sb[mid] < edge) lo = mid + 1; else hi = mid;
        }
        float4 cl;
        cl.x = (lo < 255) ? sb[lo] : __int_as_float(0x7f800000);  // +inf
        cl.y = sc[lo];
        cl.z = (lo < 255) ? sc[lo + 1] : sc[255];
        cl.w = 0.0f;
        ((float4*)(ws + 16))[k] = cl;
    }
    if (blockIdx.x == 0 && tid == 0) {
        float m = sc[0];
        for (int i = 1; i < 256; ++i) m = fmaxf(m, sc[i]);
        ws[0] = m;
    }
}

// ---------------- cross-lane helpers (all on the VALU pipe, zero LDS ops) ----
__device__ __forceinline__ float dpp_xor1(float x) {   // quad_perm [1,0,3,2]
    int i = __float_as_int(x);
    return __int_as_float(__builtin_amdgcn_update_dpp(i, i, 0xB1, 0xF, 0xF, true));
}
__device__ __forceinline__ float dpp_xor2(float x) {   // quad_perm [2,3,0,1]
    int i = __float_as_int(x);
    return __int_as_float(__builtin_amdgcn_update_dpp(i, i, 0x4E, 0xF, 0xF, true));
}
// xor-4 exchange, VARIANT A — verified PASS in round 5 (absmax 0.0156).
//   banks 0,2 ((lane&4)==0) need partner i+4 -> row_shl:4, bank_mask 0x5
//   banks 1,3 ((lane&4)==4) need partner i-4 -> row_shr:4, bank_mask 0xA
__device__ __forceinline__ float dpp_xor4(float x) {
    int i = __float_as_int(x);
    int t = __builtin_amdgcn_update_dpp(i, i, 0x104, 0xF, 0x5, false); // row_shl:4 -> banks 0,2
    t = __builtin_amdgcn_update_dpp(t, i, 0x114, 0xF, 0xA, false);     // row_shr:4 -> banks 1,3
    return __int_as_float(t);
}

__device__ __forceinline__ float rsum8(float v) {
    v += dpp_xor1(v);
    v += dpp_xor2(v);
    v += dpp_xor4(v);
    return v;
}
__device__ __forceinline__ float rmax8(float v) {
    v = fmaxf(v, dpp_xor1(v));
    v = fmaxf(v, dpp_xor2(v));
    v = fmaxf(v, dpp_xor4(v));
    return v;
}

// FWHT-128: element j = c*32 + l*4 + e; within-lane stages h=1,2 (e bits) and
// h=32,64 (c bits); cross-lane stages h=4,8,16 via DPP xor 1,2,4.
__device__ __forceinline__ void fwht128(float v[16], float s1, float s2, float s4) {
#pragma unroll
    for (int c = 0; c < 4; ++c) {           // h=1, h=2 (radix-4)
        int b = c * 4;
        float a0 = v[b], a1 = v[b + 1], a2 = v[b + 2], a3 = v[b + 3];
        float t0 = a0 + a1, t1 = a0 - a1, t2 = a2 + a3, t3 = a2 - a3;
        v[b] = t0 + t2; v[b + 1] = t1 + t3; v[b + 2] = t0 - t2; v[b + 3] = t1 - t3;
    }
#pragma unroll
    for (int i = 0; i < 16; ++i) { float t = dpp_xor1(v[i]); v[i] = fmaf(s1, v[i], t); }  // h=4
#pragma unroll
    for (int i = 0; i < 16; ++i) { float t = dpp_xor2(v[i]); v[i] = fmaf(s2, v[i], t); }  // h=8
#pragma unroll
    for (int i = 0; i < 16; ++i) { float t = dpp_xor4(v[i]); v[i] = fmaf(s4, v[i], t); }  // h=16
#pragma unroll
    for (int e = 0; e < 4; ++e) {           // h=32, h=64 (radix-4 over c)
        float a0 = v[e], a1 = v[4 + e], a2 = v[8 + e], a3 = v[12 + e];
        float t0 = a0 + a1, t1 = a0 - a1, t2 = a2 + a3, t3 = a2 - a3;
        v[e] = t0 + t2; v[4 + e] = t1 + t3; v[8 + e] = t0 - t2; v[12 + e] = t1 - t3;
    }
}

// Fused cell: one ds_read_b128 per lookup, no dependent second read.
__device__ __forceinline__ float qlook(float u, const float4* sCell) {
    float t = (u - TAB_LO) * TAB_INVSTEP;
    int k = (int)t;
    k = k < 0 ? 0 : (k > NCELL - 1 ? NCELL - 1 : k);
    float4 cl = sCell[k];
    return (cl.x < u) ? cl.z : cl.y;   // searchsorted 'left' correction
}

// ---------------- main kernel ----------------
__global__ __launch_bounds__(256) void tq_main(const float* __restrict__ x,
                                               const float* __restrict__ signs,
                                               const float* __restrict__ ws,
                                               float* __restrict__ out,
                                               int ntiles) {
    __shared__ float4 sCell[NCELL];   // 20480 B -> 8 blocks/CU by LDS
    int tid = threadIdx.x;
    const float4* wcell = (const float4*)(ws + 16);
    for (int i = tid; i < NCELL; i += 256) sCell[i] = wcell[i];
    float maxc = ws[0];
    __syncthreads();

    int lane = tid & 63;
    int wv = tid >> 6;      // wave in block: 0..3
    int g = lane >> 3;      // row within wave: 0..7
    int l = lane & 7;       // lane within row-group: 0..7
    float s1 = (l & 1) ? -1.0f : 1.0f;
    float s2 = (l & 2) ? -1.0f : 1.0f;
    float s4 = (l & 4) ? -1.0f : 1.0f;

    // this lane's 16 sign values (j = c*32 + l*4 + e)
    float sg[16];
#pragma unroll
    for (int c = 0; c < 4; ++c) {
        float4 t4 = *(const float4*)(signs + c * 32 + l * 4);
        sg[c * 4 + 0] = t4.x; sg[c * 4 + 1] = t4.y; sg[c * 4 + 2] = t4.z; sg[c * 4 + 3] = t4.w;
    }

    for (int tile = blockIdx.x; tile < ntiles; tile += gridDim.x) {
        int row = tile * 32 + wv * 8 + g;
        const float* xp = x + (size_t)row * 128;
        float v[16];
#pragma unroll
        for (int c = 0; c < 4; ++c) {
            float4 t4 = *(const float4*)(xp + c * 32 + l * 4);
            v[c * 4 + 0] = t4.x; v[c * 4 + 1] = t4.y; v[c * 4 + 2] = t4.z; v[c * 4 + 3] = t4.w;
        }
        // ---- norm ----
        float ssum = 0.0f;
#pragma unroll
        for (int i = 0; i < 16; ++i) ssum = fmaf(v[i], v[i], ssum);
        ssum = rsum8(ssum);
        float norm = sqrtf(ssum) + EPSF;
        float invn = 1.0f / norm;
        // ---- rotate ----
#pragma unroll
        for (int i = 0; i < 16; ++i) v[i] = v[i] * invn * sg[i];
        fwht128(v, s1, s2, s4);
#pragma unroll
        for (int i = 0; i < 16; ++i) v[i] *= SCALE_128;
        // ---- stats ----
        float mx = 0.0f, sm = 0.0f;
#pragma unroll
        for (int i = 0; i < 16; ++i) { float a = fabsf(v[i]); mx = fmaxf(mx, a); sm += a; }
        mx = rmax8(mx);
        sm = rsum8(sm);
        float meanv = sm * 0.0078125f + EPSF;   // /128
        float rms = mx / maxc;
        bool spiky = (mx / meanv) > 5.0f;
        // ---- pass 1 ----
        float invd = 1.0f / (rms + EPSF);
        float dxr = 0.0f, drr = 0.0f;
#pragma unroll
        for (int i = 0; i < 16; ++i) {
            float r = qlook(v[i] * invd, sCell);
            dxr = fmaf(v[i], r, dxr);
            drr = fmaf(r, r, drr);
        }
        dxr = rsum8(dxr); drr = rsum8(drr);
        float g1 = dxr / (drr + EPSF);
        // ---- pass 2 ----
        float invg = 1.0f / (g1 + EPSF);
        float rr[16];
        dxr = 0.0f; drr = 0.0f;
#pragma unroll
        for (int i = 0; i < 16; ++i) {
            float r = qlook(v[i] * invg, sCell);
            rr[i] = r;
            dxr = fmaf(v[i], r, dxr);
            drr = fmaf(r, r, drr);
        }
        dxr = rsum8(dxr); drr = rsum8(drr);
        float g2 = dxr / (drr + EPSF);
        float gamma = spiky ? rms : g2;
        if (spiky) {   // rare: re-gather r1 for spiky rows
#pragma unroll
            for (int i = 0; i < 16; ++i) rr[i] = qlook(v[i] * invd, sCell);
        }
        // ---- reconstruct ----
#pragma unroll
        for (int i = 0; i < 16; ++i) rr[i] *= gamma;
        fwht128(rr, s1, s2, s4);
        float fsc = SCALE_128 * norm;
        float* op = out + (size_t)row * 128;
#pragma unroll
        for (int c = 0; c < 4; ++c) {
            float4 o4;
            o4.x = rr[c * 4 + 0] * sg[c * 4 + 0] * fsc;
            o4.y = rr[c * 4 + 1] * sg[c * 4 + 1] * fsc;
            o4.z = rr[c * 4 + 2] * sg[c * 4 + 2] * fsc;
            o4.w = rr[c * 4 + 3] * sg[c * 4 + 3] * fsc;
            *(float4*)(op + c * 32 + l * 4) = o4;
        }
    }
}

extern "C" void kernel_launch(void* const* d_in, const int* in_sizes, int n_in,
                              void* d_out, int out_size, void* d_ws, size_t ws_size,
                              hipStream_t stream) {
    const float* x     = (const float*)d_in[0];
    const float* signs = (const float*)d_in[1];
    const float* cent  = (const float*)d_in[2];
    float* out = (float*)d_out;
    float* ws  = (float*)d_ws;

    int nrows  = in_sizes[0] / 128;
    int ntiles = nrows / 32;     // 32 rows per block-iteration (4 waves x 8 rows)

    build_table<<<(NCELL + 255) / 256, 256, 0, stream>>>(cent, ws);
    int grid = ntiles < GRID_MAIN ? ntiles : GRID_MAIN;
    tq_main<<<grid, 256, 0, stream>>>(x, signs, ws, out, ntiles);
}